// Round 12
// baseline (3831.350 us; speedup 1.0000x reference)
//
#include <hip/hip_runtime.h>
#include <stdint.h>

#define N      12288
#define CH     512
#define TI     128               // i-rows per block
#define TJ     128               // j-cols per tile
#define KC     32                // k-chunk
#define NCH    (CH / KC)         // 16 chunks per jt
#define NIT    (N / TI)          // 96 i-tiles
#define NJT    (N / TJ)          // 96 j-tiles
#define NS     8                 // j-slices
#define JT_PER_S (NJT / NS)      // 12 j-tiles per block
#define GTOT   (JT_PER_S * NCH)  // 192 chunks per block

struct Top2 { float v0, v1; int i0, i1; };

// ---- module-scope device scratch (static, graph-capture safe) ----
__device__ float g_An[(size_t)CH * N];   // 25 MB normalized A
__device__ float g_Bn[(size_t)CH * N];   // 25 MB normalized B
__device__ Top2  g_rpart[NS][N];         // row top-2 partials (1.6 MB)
__device__ Top2  g_cpart[NIT][N];        // col top-2 partials (18.9 MB)
__device__ int   g_nn12[N];
__device__ float g_r12[N];
__device__ float g_sim0[N];
__device__ int   g_nn21[N];
__device__ float g_r21[N];

__device__ __forceinline__ void t2_ins(float v, int idx,
                                       float& v0, int& i0, float& v1, int& i1) {
  bool beats0 = (v > v0) || (v == v0 && idx < i0);
  bool beats1 = (v > v1) || (v == v1 && idx < i1);
  if (beats0) { v1 = v0; i1 = i0; v0 = v; i0 = idx; }
  else if (beats1) { v1 = v; i1 = idx; }
}

__device__ __forceinline__ float bf16_quant(float f) {
  unsigned int u = __float_as_uint(f);
  unsigned int r = 0x7fffu + ((u >> 16) & 1u);
  unsigned int q = ((u + r) >> 16) << 16;
  return __uint_as_float(q);
}

// -------------------- kernel 1: normalize descriptors --------------------
__global__ void normalize_kernel(const float* __restrict__ A,
                                 const float* __restrict__ B) {
  int i = blockIdx.x * 256 + threadIdx.x;
  if (i >= N) return;
  float sa = 0.f, sb = 0.f;
  for (int c = 0; c < CH; ++c) {
    float a = A[(size_t)c * N + i];
    float b = B[(size_t)c * N + i];
    sa += a * a;
    sb += b * b;
  }
  float na = sqrtf(sa), nb = sqrtf(sb);
  for (int c = 0; c < CH; ++c) {
    g_An[(size_t)c * N + i] = A[(size_t)c * N + i] / na;
    g_Bn[(size_t)c * N + i] = B[(size_t)c * N + i] / nb;
  }
}

// -------------------- kernel 2: sim GEMM (reg-prefetch staging) + row/col top-2 ----
// grid (96, 8). Thread tile 8x8 in 4x4 quadrants. Unpadded LDS, contiguous
// 1KB/wave staging writes (conflicts ~0, verified R11). Register prefetch of
// chunk g+1 hidden under chunk g's 4096-cyc FMA block.
// amdgpu_waves_per_eu(3,3): pin occupancy target to what LDS (42KB -> 3
// blocks/CU) allows anyway -> VGPR budget ~170 -> NO SPILLS. The allocator's
// default high-occupancy heuristic chose 72 VGPRs in R11 and spilled the
// prefetch regs (3.3 GB scratch writes = the whole 3.9ms runtime).
__global__ __launch_bounds__(256) __attribute__((amdgpu_waves_per_eu(3, 3)))
void sim_kernel() {
  __shared__ float Xs[KC * TI];      // 16 KB
  __shared__ float Ys[KC * TJ];      // 16 KB
  __shared__ Top2  rowTop[TI];       // 2 KB
  __shared__ Top2  colWave[4][TJ];   // 8 KB

  const int itile = blockIdx.x;
  const int slice = blockIdx.y;
  const int i0 = itile * TI;
  const int tid  = threadIdx.x;
  const int tx = tid & 15;
  const int ty = tid >> 4;       // 0..15
  const int w  = tid >> 6;       // wave 0..3
  const int lane = tid & 63;

  if (tid < TI) {
    rowTop[tid].v0 = -1e30f; rowTop[tid].v1 = -1e30f;
    rowTop[tid].i0 = 0x7fffffff; rowTop[tid].i1 = 0x7fffffff;
  }

  // staging map: inst t (0..3) <-> LDS word 1024t + 4*tid
  //   = row k = 8t + (tid>>5), col c = (tid&31)*4  (global: coalesced 512B/32 lanes)
  const int lk = tid >> 5;          // 0..7
  const int lc = (tid & 31) * 4;    // 0..124

  float4 px[4], py[4];

#define LOAD_CHUNK(G)                                                          \
  {                                                                            \
    const int jt_ = (G) >> 4, cc_ = (G) & 15;                                  \
    const int kc_ = cc_ * KC;                                                  \
    const int j0_ = (slice * JT_PER_S + jt_) * TJ;                             \
    _Pragma("unroll")                                                          \
    for (int t = 0; t < 4; ++t) {                                              \
      const size_t krow = (size_t)(kc_ + 8 * t + lk) * N;                      \
      px[t] = *reinterpret_cast<const float4*>(&g_An[krow + i0 + lc]);         \
      py[t] = *reinterpret_cast<const float4*>(&g_Bn[krow + j0_ + lc]);        \
    }                                                                          \
  }

  LOAD_CHUNK(0);
  int g = 0;
  float acc[8][8];

  for (int jt = 0; jt < JT_PER_S; ++jt) {
    const int j0 = (slice * JT_PER_S + jt) * TJ;
#pragma unroll
    for (int u = 0; u < 8; ++u)
#pragma unroll
      for (int v = 0; v < 8; ++v) acc[u][v] = 0.f;

    for (int cc = 0; cc < NCH; ++cc, ++g) {
      __syncthreads();                 // prev chunk's LDS readers done
#pragma unroll
      for (int t = 0; t < 4; ++t) {    // contiguous wave writes: no conflicts
        *reinterpret_cast<float4*>(&Xs[t * 1024 + tid * 4]) = px[t];
        *reinterpret_cast<float4*>(&Ys[t * 1024 + tid * 4]) = py[t];
      }
      __syncthreads();
      if (g + 1 < GTOT) LOAD_CHUNK(g + 1);   // prefetch: hidden under compute

#pragma unroll 8
      for (int k = 0; k < KC; ++k) {
        float a[8] __attribute__((aligned(16)));
        float b[8] __attribute__((aligned(16)));
        *reinterpret_cast<float4*>(&a[0]) = *reinterpret_cast<const float4*>(&Xs[k * TI + ty * 4]);
        *reinterpret_cast<float4*>(&a[4]) = *reinterpret_cast<const float4*>(&Xs[k * TI + 64 + ty * 4]);
        *reinterpret_cast<float4*>(&b[0]) = *reinterpret_cast<const float4*>(&Ys[k * TJ + tx * 4]);
        *reinterpret_cast<float4*>(&b[4]) = *reinterpret_cast<const float4*>(&Ys[k * TJ + 64 + tx * 4]);
#pragma unroll
        for (int u = 0; u < 8; ++u)
#pragma unroll
          for (int v = 0; v < 8; ++v)
            acc[u][v] += a[u] * b[v];
      }
    }

    // ---- epilogue (verified absmax 0): acc IS cosine sim ----
    // row top-2: reduce across tx (masks 1..8)
#pragma unroll
    for (int u = 0; u < 8; ++u) {
      float v0 = -1e30f, v1 = -1e30f; int id0 = 0x7fffffff, id1 = 0x7fffffff;
#pragma unroll
      for (int v = 0; v < 8; ++v) {
        int col = (v >> 2) * 64 + tx * 4 + (v & 3);
        t2_ins(acc[u][v], j0 + col, v0, id0, v1, id1);
      }
#pragma unroll
      for (int m = 1; m < 16; m <<= 1) {
        float ov0 = __shfl_xor(v0, m), ov1 = __shfl_xor(v1, m);
        int   oi0 = __shfl_xor(id0, m), oi1 = __shfl_xor(id1, m);
        t2_ins(ov0, oi0, v0, id0, v1, id1);
        t2_ins(ov1, oi1, v0, id0, v1, id1);
      }
      if (tx == 0) {   // unique owner per row
        int row = (u >> 2) * 64 + ty * 4 + (u & 3);
        Top2 t = rowTop[row];
        t2_ins(v0, id0, t.v0, t.i0, t.v1, t.i1);
        t2_ins(v1, id1, t.v0, t.i0, t.v1, t.i1);
        rowTop[row] = t;
      }
    }

    // col top-2: reduce 8 local rows, then across ty in-wave (masks 16,32)
#pragma unroll
    for (int v = 0; v < 8; ++v) {
      float v0 = -1e30f, v1 = -1e30f; int id0 = 0x7fffffff, id1 = 0x7fffffff;
#pragma unroll
      for (int u = 0; u < 8; ++u) {
        int row = (u >> 2) * 64 + ty * 4 + (u & 3);
        t2_ins(acc[u][v], i0 + row, v0, id0, v1, id1);
      }
#pragma unroll
      for (int m = 16; m < 64; m <<= 1) {
        float ov0 = __shfl_xor(v0, m), ov1 = __shfl_xor(v1, m);
        int   oi0 = __shfl_xor(id0, m), oi1 = __shfl_xor(id1, m);
        t2_ins(ov0, oi0, v0, id0, v1, id1);
        t2_ins(ov1, oi1, v0, id0, v1, id1);
      }
      if ((lane >> 4) == 0) {
        int col = (v >> 2) * 64 + tx * 4 + (v & 3);
        Top2 t; t.v0 = v0; t.v1 = v1; t.i0 = id0; t.i1 = id1;
        colWave[w][col] = t;
      }
    }
    __syncthreads();
    if (tid < TJ) {
      Top2 t = colWave[0][tid];
#pragma unroll
      for (int ww = 1; ww < 4; ++ww) {
        Top2 o = colWave[ww][tid];
        t2_ins(o.v0, o.i0, t.v0, t.i0, t.v1, t.i1);
        t2_ins(o.v1, o.i1, t.v0, t.i0, t.v1, t.i1);
      }
      g_cpart[itile][j0 + tid] = t;
    }
  }

  __syncthreads();
  if (tid < TI) g_rpart[slice][i0 + tid] = rowTop[tid];
#undef LOAD_CHUNK
}

// -------------------- kernel 3: merge partials --------------------
__global__ void merge_kernel() {
  int i = blockIdx.x * 256 + threadIdx.x;
  if (i >= N) return;
  {
    float v0 = -1e30f, v1 = -1e30f; int id0 = 0x7fffffff, id1 = 0x7fffffff;
#pragma unroll
    for (int s = 0; s < NS; ++s) {
      Top2 p = g_rpart[s][i];
      t2_ins(p.v0, p.i0, v0, id0, v1, id1);
      t2_ins(p.v1, p.i1, v0, id0, v1, id1);
    }
    float d0 = 2.f - 2.f * v0, d1 = 2.f - 2.f * v1;
    g_nn12[i] = id0; g_r12[i] = d0 / (d1 + 1e-8f); g_sim0[i] = v0;
  }
  {
    float v0 = -1e30f, v1 = -1e30f; int id0 = 0x7fffffff, id1 = 0x7fffffff;
    for (int p = 0; p < NIT; ++p) {
      Top2 t = g_cpart[p][i];
      t2_ins(t.v0, t.i0, v0, id0, v1, id1);
      t2_ins(t.v1, t.i1, v0, id0, v1, id1);
    }
    float d0 = 2.f - 2.f * v0, d1 = 2.f - 2.f * v1;
    g_nn21[i] = id0; g_r21[i] = d0 / (d1 + 1e-8f);
  }
}

// -------------------- kernel 4: mutual-NN + ratio mask, FP32 outputs ----------
__global__ void finalize_kernel(float* __restrict__ out) {
  int i = blockIdx.x * 256 + threadIdx.x;
  if (i >= N) return;
  int j = g_nn12[i];
  int jc = j < 0 ? 0 : (j >= N ? N - 1 : j);
  bool mask = (g_nn21[jc] == i) && (g_r12[i] <= 0.95f) && (g_r21[jc] <= 0.95f);
  out[i]         = bf16_quant(mask ? g_sim0[i] : 0.f);
  out[N + i]     = bf16_quant((float)j);
  out[2 * N + i] = mask ? 1.f : 0.f;
}

extern "C" void kernel_launch(void* const* d_in, const int* in_sizes, int n_in,
                              void* d_out, int out_size, void* d_ws, size_t ws_size,
                              hipStream_t stream) {
  const float* A = (const float*)d_in[0];  // fp32 [CH][N]
  const float* B = (const float*)d_in[1];
  (void)d_ws; (void)ws_size;

  normalize_kernel<<<dim3((N + 255) / 256), 256, 0, stream>>>(A, B);
  sim_kernel<<<dim3(NIT, NS), 256, 0, stream>>>();
  merge_kernel<<<dim3((N + 255) / 256), 256, 0, stream>>>();
  finalize_kernel<<<dim3((N + 255) / 256), 256, 0, stream>>>((float*)d_out);
}

// Round 13
// 2923.415 us; speedup vs baseline: 1.3106x; 1.3106x over previous
//
#include <hip/hip_runtime.h>
#include <stdint.h>

#define N      12288
#define CH     512
#define TI     128               // i-rows per block
#define TJ     128               // j-cols per tile
#define KC     32                // k-chunk
#define NCH    (CH / KC)         // 16 chunks per jt
#define NIT    (N / TI)          // 96 i-tiles
#define NJT    (N / TJ)          // 96 j-tiles
#define NS     8                 // j-slices
#define JT_PER_S (NJT / NS)      // 12 j-tiles per block

struct Top2 { float v0, v1; int i0, i1; };

// ---- module-scope device scratch (static, graph-capture safe) ----
__device__ float g_An[(size_t)CH * N];   // 25 MB normalized A
__device__ float g_Bn[(size_t)CH * N];   // 25 MB normalized B
__device__ Top2  g_rpart[NS][N];         // row top-2 partials (1.6 MB)
__device__ Top2  g_cpart[NIT][N];        // col top-2 partials (18.9 MB)
__device__ int   g_nn12[N];
__device__ float g_r12[N];
__device__ float g_sim0[N];
__device__ int   g_nn21[N];
__device__ float g_r21[N];

__device__ __forceinline__ void t2_ins(float v, int idx,
                                       float& v0, int& i0, float& v1, int& i1) {
  bool beats0 = (v > v0) || (v == v0 && idx < i0);
  bool beats1 = (v > v1) || (v == v1 && idx < i1);
  if (beats0) { v1 = v0; i1 = i0; v0 = v; i0 = idx; }
  else if (beats1) { v1 = v; i1 = idx; }
}

__device__ __forceinline__ float bf16_quant(float f) {
  unsigned int u = __float_as_uint(f);
  unsigned int r = 0x7fffu + ((u >> 16) & 1u);
  unsigned int q = ((u + r) >> 16) << 16;
  return __uint_as_float(q);
}

// -------------------- kernel 1: normalize descriptors --------------------
__global__ void normalize_kernel(const float* __restrict__ A,
                                 const float* __restrict__ B) {
  int i = blockIdx.x * 256 + threadIdx.x;
  if (i >= N) return;
  float sa = 0.f, sb = 0.f;
  for (int c = 0; c < CH; ++c) {
    float a = A[(size_t)c * N + i];
    float b = B[(size_t)c * N + i];
    sa += a * a;
    sb += b * b;
  }
  float na = sqrtf(sa), nb = sqrtf(sb);
  for (int c = 0; c < CH; ++c) {
    g_An[(size_t)c * N + i] = A[(size_t)c * N + i] / na;
    g_Bn[(size_t)c * N + i] = B[(size_t)c * N + i] / nb;
  }
}

// -------------------- kernel 2: sim GEMM + row/col top-2 --------------------
// grid (96, 8). Thread tile 8x8 in 4x4 quadrants. Two-barrier chunk loop with
// SHORT-LIVED staging regs only (R8-proven: VGPR 80, no spills — this clang
// spills anything live across the FMA block, targeting ~72 VGPRs regardless
// of launch_bounds/waves_per_eu hints; R9/R11/R12 all spill-bound).
// Staging map (R11-proven conflict-free): inst t <-> LDS word 1024t + 4*tid
// = row k=8t+(tid>>5), col (tid&31)*4; contiguous 1KB/wave writes.
// Latency hiding: 3 blocks/CU stagger staging vs compute phases.
__global__ __launch_bounds__(256)
void sim_kernel() {
  __shared__ float Xs[KC * TI];      // 16 KB (unpadded)
  __shared__ float Ys[KC * TJ];      // 16 KB
  __shared__ Top2  rowTop[TI];       // 2 KB
  __shared__ Top2  colWave[4][TJ];   // 8 KB

  const int itile = blockIdx.x;
  const int slice = blockIdx.y;
  const int i0 = itile * TI;
  const int tid  = threadIdx.x;
  const int tx = tid & 15;
  const int ty = tid >> 4;       // 0..15
  const int w  = tid >> 6;       // wave 0..3
  const int lane = tid & 63;

  if (tid < TI) {
    rowTop[tid].v0 = -1e30f; rowTop[tid].v1 = -1e30f;
    rowTop[tid].i0 = 0x7fffffff; rowTop[tid].i1 = 0x7fffffff;
  }

  const int lk = tid >> 5;          // 0..7
  const int lc = (tid & 31) * 4;    // 0..124
  const float* gxb = g_An + i0 + lc;

  float acc[8][8];

  for (int jt = 0; jt < JT_PER_S; ++jt) {
    const int j0 = (slice * JT_PER_S + jt) * TJ;
    const float* gyb = g_Bn + j0 + lc;
#pragma unroll
    for (int u = 0; u < 8; ++u)
#pragma unroll
      for (int v = 0; v < 8; ++v) acc[u][v] = 0.f;

    for (int cc = 0; cc < NCH; ++cc) {
      const int kc = cc * KC;
      __syncthreads();                 // barrier-1: prev chunk's readers done
      {
        // 8 outstanding loads, then 8 LDS stores: liveness spans only this
        // block -> no spill; global addrs coalesced 512B/32-lane groups.
        float4 vx[4], vy[4];
#pragma unroll
        for (int t = 0; t < 4; ++t) {
          const size_t krow = (size_t)(kc + 8 * t + lk) * N;
          vx[t] = *reinterpret_cast<const float4*>(gxb + krow);
          vy[t] = *reinterpret_cast<const float4*>(gyb + krow);
        }
#pragma unroll
        for (int t = 0; t < 4; ++t) {  // contiguous wave writes: no conflicts
          *reinterpret_cast<float4*>(&Xs[t * 1024 + tid * 4]) = vx[t];
          *reinterpret_cast<float4*>(&Ys[t * 1024 + tid * 4]) = vy[t];
        }
      }
      __syncthreads();                 // barrier-2: LDS ready

#pragma unroll 8
      for (int k = 0; k < KC; ++k) {
        float a[8] __attribute__((aligned(16)));
        float b[8] __attribute__((aligned(16)));
        *reinterpret_cast<float4*>(&a[0]) = *reinterpret_cast<const float4*>(&Xs[k * TI + ty * 4]);
        *reinterpret_cast<float4*>(&a[4]) = *reinterpret_cast<const float4*>(&Xs[k * TI + 64 + ty * 4]);
        *reinterpret_cast<float4*>(&b[0]) = *reinterpret_cast<const float4*>(&Ys[k * TJ + tx * 4]);
        *reinterpret_cast<float4*>(&b[4]) = *reinterpret_cast<const float4*>(&Ys[k * TJ + 64 + tx * 4]);
#pragma unroll
        for (int u = 0; u < 8; ++u)
#pragma unroll
          for (int v = 0; v < 8; ++v)
            acc[u][v] += a[u] * b[v];
      }
    }

    // ---- epilogue (verified absmax 0): acc IS cosine sim ----
    // row top-2: reduce across tx (masks 1..8)
#pragma unroll
    for (int u = 0; u < 8; ++u) {
      float v0 = -1e30f, v1 = -1e30f; int id0 = 0x7fffffff, id1 = 0x7fffffff;
#pragma unroll
      for (int v = 0; v < 8; ++v) {
        int col = (v >> 2) * 64 + tx * 4 + (v & 3);
        t2_ins(acc[u][v], j0 + col, v0, id0, v1, id1);
      }
#pragma unroll
      for (int m = 1; m < 16; m <<= 1) {
        float ov0 = __shfl_xor(v0, m), ov1 = __shfl_xor(v1, m);
        int   oi0 = __shfl_xor(id0, m), oi1 = __shfl_xor(id1, m);
        t2_ins(ov0, oi0, v0, id0, v1, id1);
        t2_ins(ov1, oi1, v0, id0, v1, id1);
      }
      if (tx == 0) {   // unique owner per row
        int row = (u >> 2) * 64 + ty * 4 + (u & 3);
        Top2 t = rowTop[row];
        t2_ins(v0, id0, t.v0, t.i0, t.v1, t.i1);
        t2_ins(v1, id1, t.v0, t.i0, t.v1, t.i1);
        rowTop[row] = t;
      }
    }

    // col top-2: reduce 8 local rows, then across ty in-wave (masks 16,32)
#pragma unroll
    for (int v = 0; v < 8; ++v) {
      float v0 = -1e30f, v1 = -1e30f; int id0 = 0x7fffffff, id1 = 0x7fffffff;
#pragma unroll
      for (int u = 0; u < 8; ++u) {
        int row = (u >> 2) * 64 + ty * 4 + (u & 3);
        t2_ins(acc[u][v], i0 + row, v0, id0, v1, id1);
      }
#pragma unroll
      for (int m = 16; m < 64; m <<= 1) {
        float ov0 = __shfl_xor(v0, m), ov1 = __shfl_xor(v1, m);
        int   oi0 = __shfl_xor(id0, m), oi1 = __shfl_xor(id1, m);
        t2_ins(ov0, oi0, v0, id0, v1, id1);
        t2_ins(ov1, oi1, v0, id0, v1, id1);
      }
      if ((lane >> 4) == 0) {
        int col = (v >> 2) * 64 + tx * 4 + (v & 3);
        Top2 t; t.v0 = v0; t.v1 = v1; t.i0 = id0; t.i1 = id1;
        colWave[w][col] = t;
      }
    }
    __syncthreads();
    if (tid < TJ) {
      Top2 t = colWave[0][tid];
#pragma unroll
      for (int ww = 1; ww < 4; ++ww) {
        Top2 o = colWave[ww][tid];
        t2_ins(o.v0, o.i0, t.v0, t.i0, t.v1, t.i1);
        t2_ins(o.v1, o.i1, t.v0, t.i0, t.v1, t.i1);
      }
      g_cpart[itile][j0 + tid] = t;
    }
  }

  __syncthreads();
  if (tid < TI) g_rpart[slice][i0 + tid] = rowTop[tid];
}

// -------------------- kernel 3: merge partials --------------------
__global__ void merge_kernel() {
  int i = blockIdx.x * 256 + threadIdx.x;
  if (i >= N) return;
  {
    float v0 = -1e30f, v1 = -1e30f; int id0 = 0x7fffffff, id1 = 0x7fffffff;
#pragma unroll
    for (int s = 0; s < NS; ++s) {
      Top2 p = g_rpart[s][i];
      t2_ins(p.v0, p.i0, v0, id0, v1, id1);
      t2_ins(p.v1, p.i1, v0, id0, v1, id1);
    }
    float d0 = 2.f - 2.f * v0, d1 = 2.f - 2.f * v1;
    g_nn12[i] = id0; g_r12[i] = d0 / (d1 + 1e-8f); g_sim0[i] = v0;
  }
  {
    float v0 = -1e30f, v1 = -1e30f; int id0 = 0x7fffffff, id1 = 0x7fffffff;
    for (int p = 0; p < NIT; ++p) {
      Top2 t = g_cpart[p][i];
      t2_ins(t.v0, t.i0, v0, id0, v1, id1);
      t2_ins(t.v1, t.i1, v0, id0, v1, id1);
    }
    float d0 = 2.f - 2.f * v0, d1 = 2.f - 2.f * v1;
    g_nn21[i] = id0; g_r21[i] = d0 / (d1 + 1e-8f);
  }
}

// -------------------- kernel 4: mutual-NN + ratio mask, FP32 outputs ----------
__global__ void finalize_kernel(float* __restrict__ out) {
  int i = blockIdx.x * 256 + threadIdx.x;
  if (i >= N) return;
  int j = g_nn12[i];
  int jc = j < 0 ? 0 : (j >= N ? N - 1 : j);
  bool mask = (g_nn21[jc] == i) && (g_r12[i] <= 0.95f) && (g_r21[jc] <= 0.95f);
  out[i]         = bf16_quant(mask ? g_sim0[i] : 0.f);
  out[N + i]     = bf16_quant((float)j);
  out[2 * N + i] = mask ? 1.f : 0.f;
}

extern "C" void kernel_launch(void* const* d_in, const int* in_sizes, int n_in,
                              void* d_out, int out_size, void* d_ws, size_t ws_size,
                              hipStream_t stream) {
  const float* A = (const float*)d_in[0];  // fp32 [CH][N]
  const float* B = (const float*)d_in[1];
  (void)d_ws; (void)ws_size;

  normalize_kernel<<<dim3((N + 255) / 256), 256, 0, stream>>>(A, B);
  sim_kernel<<<dim3(NIT, NS), 256, 0, stream>>>();
  merge_kernel<<<dim3((N + 255) / 256), 256, 0, stream>>>();
  finalize_kernel<<<dim3((N + 255) / 256), 256, 0, stream>>>((float*)d_out);
}